// Round 10
// baseline (157.025 us; speedup 1.0000x reference)
//
#include <hip/hip_runtime.h>
#include <hip/hip_bf16.h>
#include <stdint.h>

#define NB    2048
#define NSENT 20
#define SEC   40
#define DD    100
#define UU    50
#define SP1   801
#define STRIDE 136      // shorts per LDS h row; 272 B
#define TROWS 80        // rows per tile = 2 sentences
#define TGRAN 2000      // 16B granules per tile (80*100*4/16)
#define MAXG  20024     // last valid granule inside one document

typedef short bf16x8 __attribute__((ext_vector_type(8)));
typedef float f32x4 __attribute__((ext_vector_type(4)));

__device__ __forceinline__ unsigned f2bf(float f) {
  unsigned u = __float_as_uint(f);
  return (u + 0x7fffu + ((u >> 16) & 1u)) >> 16;   // RNE
}
__device__ __forceinline__ float rlane(float v, int l) {
  return __uint_as_float(__builtin_amdgcn_readlane(__float_as_uint(v), l));
}

// One 4-wave block per document b; each iteration covers TWO sentences
// (80 h rows). Wave w owns u-tile w of C[u][s]=wh·h^T over all 5 s-tiles.
// wub folded into MFMA via bias column k=100 (h[s][100]=1, A[u][100]=wub_u).
// Depth-2 register prefetch (stA/stB), dbuf LDS, 2 barriers per 2 sentences.
__global__ __launch_bounds__(256, 3) void doc_kernel(
    const float* __restrict__ inputs, const float* __restrict__ vw,
    const float* __restrict__ wh, const float* __restrict__ wu,
    const float* __restrict__ bw, float* __restrict__ out) {
  __shared__ __align__(16) unsigned short hs[2][TROWS * STRIDE]; // 2x21760 B
  __shared__ __align__(16) float epart[5 * 16 * 4];              // [st][col][w]

  const int tid  = threadIdx.x;
  const int w    = tid >> 6, lane = tid & 63;
  const int col  = lane & 15, grp = lane >> 4;
  const int b    = blockIdx.x;

  const float4* base4 = (const float4*)(inputs + (size_t)b * SP1 * DD);

  // ---- depth-2 prologue: tile 0 -> stA, tile 1 -> stB (clamped granules) ----
  float4 stA[8], stB[8];
  #pragma unroll
  for (int j = 0; j < 8; ++j) stA[j] = base4[min(j * 256 + tid, MAXG)];
  #pragma unroll
  for (int j = 0; j < 8; ++j) stB[j] = base4[min(TGRAN + j * 256 + tid, MAXG)];

  // ---- zero both h buffers; fold in bias column h[row][100] = 1.0 ----
  // uint4 chunk c of a row covers bytes 16c..16c+15; chunk 12 holds shorts
  // 96..103, so col 100 = .z low half. Row stride = 17 chunks (272 B).
  {
    #pragma unroll 1
    for (int i = tid; i < 2 * TROWS * STRIDE / 8; i += 256) {
      uint4 z; z.x = z.y = 0u; z.w = 0u;
      z.z = ((i % 17) == 12) ? 0x00003F80u : 0u;
      ((uint4*)&hs[0][0])[i] = z;
    }
  }

  // ---- convert-pass byte addresses (fixed per thread) ----
  int cvta[8];
  #pragma unroll
  for (int j = 0; j < 8; ++j) {
    int idx = j * 256 + tid;
    int row = idx / 25, c4 = idx - row * 25;
    cvta[j] = row * 272 + c4 * 8;
  }

  // ---- wub[u=lane] = uvec[b]·wu[u] + bw[u] (each wave redundantly) ----
  float wubacc;
  {
    int ur = lane < UU ? lane : UU - 1;
    const float4* uv4 = (const float4*)(inputs + ((size_t)b * SP1 + SP1 - 1) * DD);
    const float4* wr4 = (const float4*)(wu + ur * DD);
    float a0 = bw[ur];
    #pragma unroll 5
    for (int q = 0; q < 25; ++q) {
      float4 uq = uv4[q], wq = wr4[q];
      a0 = fmaf(uq.x, wq.x, a0); a0 = fmaf(uq.y, wq.y, a0);
      a0 = fmaf(uq.z, wq.z, a0); a0 = fmaf(uq.w, wq.w, a0);
    }
    wubacc = a0;
  }

  // ---- A fragments: this wave's 16 wh rows (u = 16w + col), resident;
  //      k=100 element of kt=3/grp=0 carries the wub_u bias ----
  bf16x8 afrag[4];
  {
    int u = w * 16 + col;
    float wv = __shfl(wubacc, u & 63);   // wub for THIS lane's A-row
    #pragma unroll
    for (int kt = 0; kt < 4; ++kt) {
      bf16x8 f;
      #pragma unroll
      for (int j = 0; j < 8; ++j) {
        int k = kt * 32 + grp * 8 + j;
        float v = (u < UU && k < DD) ? wh[u * DD + k] : 0.f;
        f[j] = (short)f2bf(v);
      }
      if (kt == 3 && grp == 0 && u < UU) f[4] = (short)f2bf(wv); // k=100
      afrag[kt] = f;
    }
  }

  float vwr[4];
  #pragma unroll
  for (int r = 0; r < 4; ++r) {
    int u = w * 16 + grp * 4 + r;
    vwr[r] = (u < UU) ? vw[u] : 0.f;
  }

  __syncthreads();   // B0: zero-fill + bias col visible

  float* outb = out + (size_t)b * NSENT * DD;
  const int sent = w >> 1, dh = w & 1;      // out-phase roles

#define TILE_BODY(stg, t)                                                      \
  {                                                                            \
    unsigned char* hc = (unsigned char*)&hs[(t) & 1][0];                       \
    /* convert tile t (stage regs) -> bf16 LDS via v_cvt_pk */                 \
    _Pragma("unroll")                                                          \
    for (int j = 0; j < 8; ++j) {                                              \
      int idx = j * 256 + tid;                                                 \
      if (j < 7 || idx < TGRAN) {                                              \
        unsigned o0, o1;                                                       \
        asm("v_cvt_pk_bf16_f32 %0, %1, %2" : "=v"(o0) : "v"(stg[j].x), "v"(stg[j].y)); \
        asm("v_cvt_pk_bf16_f32 %0, %1, %2" : "=v"(o1) : "v"(stg[j].z), "v"(stg[j].w)); \
        uint2 wv2; wv2.x = o0; wv2.y = o1;                                     \
        *(uint2*)(hc + cvta[j]) = wv2;                                         \
      }                                                                        \
    }                                                                          \
    /* issue tile t+2 loads into the freed stage regs */                       \
    if ((t) + 2 < NSENT / 2) {                                                 \
      _Pragma("unroll")                                                        \
      for (int j = 0; j < 8; ++j)                                              \
        stg[j] = base4[min(((t) + 2) * TGRAN + j * 256 + tid, MAXG)];          \
    }                                                                          \
    __builtin_amdgcn_sched_barrier(0);                                         \
    __syncthreads(); /* B1 */                                                  \
    /* MFMA: acc[st] = C[u-tile w][s-tile st] (+wub via bias col), st 0..4 */  \
    f32x4 acc[5];                                                              \
    _Pragma("unroll")                                                          \
    for (int st = 0; st < 5; ++st) { f32x4 z = {0.f,0.f,0.f,0.f}; acc[st] = z; } \
    _Pragma("unroll")                                                          \
    for (int kt = 0; kt < 4; ++kt) {                                           \
      _Pragma("unroll")                                                        \
      for (int st = 0; st < 5; ++st) {                                         \
        bf16x8 hf = *(const bf16x8*)(hc + (st * 16 + col) * 272 + kt * 64 + grp * 16); \
        acc[st] = __builtin_amdgcn_mfma_f32_16x16x32_bf16(afrag[kt], hf, acc[st], 0, 0, 0); \
      }                                                                        \
    }                                                                          \
    /* partial e[s]: sum over this wave's u rows (bias already in acc) */      \
    _Pragma("unroll")                                                          \
    for (int st = 0; st < 5; ++st) {                                           \
      float s = 0.f;                                                           \
      _Pragma("unroll")                                                        \
      for (int r = 0; r < 4; ++r) {                                            \
        float E = exp2f(acc[st][r] * 2.885390081777927f);   /* e^{2x} */       \
        float tt = 1.f - 2.f * __builtin_amdgcn_rcpf(E + 1.f);                 \
        s = fmaf(tt, vwr[r], s);                                               \
      }                                                                        \
      s += __shfl_xor(s, 16);                                                  \
      s += __shfl_xor(s, 32);                                                  \
      if (grp == 0) epart[st * 64 + col * 4 + w] = s;                          \
    }                                                                          \
    __syncthreads(); /* B2 */                                                  \
    /* softmax: this wave's sentence (waves 0,1->A; 2,3->B), 40 values */      \
    int srow = sent * SEC + (lane < SEC ? lane : 0);                           \
    f32x4 q = *(const f32x4*)&epart[(srow >> 4) * 64 + (srow & 15) * 4];       \
    float e = (q[0] + q[1]) + (q[2] + q[3]);                                   \
    float p = (lane < SEC) ? __expf(e) : 0.f;                                  \
    float ps = p;                                                              \
    ps += __shfl_xor(ps, 1);                                                   \
    ps += __shfl_xor(ps, 2);                                                   \
    ps += __shfl_xor(ps, 4);                                                   \
    ps += __shfl_xor(ps, 8);                                                   \
    float sum = (rlane(ps, 0) + rlane(ps, 16)) + rlane(ps, 32);                \
    float pr = p * __builtin_amdgcn_rcpf(sum);                                 \
    /* PIN: compute pr with full exec mask before divergent readlane use */    \
    asm volatile("" : "+v"(pr));                                               \
    /* out: wave w -> sentence sent, d-half dh (50 d's); alpha via readlane */ \
    if (lane < 50) {                                                           \
      int d = dh * 50 + lane;                                                  \
      const unsigned short* hp = (const unsigned short*)hc + sent * SEC * STRIDE + d; \
      float a0 = 0.f, a1 = 0.f;                                                \
      _Pragma("unroll")                                                        \
      for (int s = 0; s < SEC; s += 2) {                                       \
        float al0 = rlane(pr, s);                                              \
        float al1 = rlane(pr, s + 1);                                          \
        a0 = fmaf(al0, __uint_as_float((unsigned)hp[s * STRIDE] << 16), a0);   \
        a1 = fmaf(al1, __uint_as_float((unsigned)hp[(s + 1) * STRIDE] << 16), a1); \
      }                                                                        \
      outb[((t) * 2 + sent) * DD + d] = a0 + a1;                               \
    }                                                                          \
  }

  #pragma unroll 1
  for (int t = 0; t < NSENT / 2; t += 2) {
    TILE_BODY(stA, t)
    TILE_BODY(stB, t + 1)
  }
#undef TILE_BODY
}

extern "C" void kernel_launch(void* const* d_in, const int* in_sizes, int n_in,
                              void* d_out, int out_size, void* d_ws, size_t ws_size,
                              hipStream_t stream) {
  const float* inputs = (const float*)d_in[0];
  const float* vw     = (const float*)d_in[1];
  const float* wh     = (const float*)d_in[2];
  const float* wu     = (const float*)d_in[3];
  const float* bw     = (const float*)d_in[4];
  float* out = (float*)d_out;

  doc_kernel<<<NB, 256, 0, stream>>>(inputs, vw, wh, wu, bw, out);
}

// Round 11
// 151.467 us; speedup vs baseline: 1.0367x; 1.0367x over previous
//
#include <hip/hip_runtime.h>
#include <hip/hip_bf16.h>
#include <stdint.h>

#define NB    2048
#define NSENT 20
#define SEC   40
#define DD    100
#define UU    50
#define SP1   801
#define STRIDE 136      // shorts per LDS h row; 272 B
#define TROWS 80        // rows per tile = 2 sentences
#define TGRAN 2000      // 16B granules per tile (80*100*4/16)
#define MAXG  20024     // last valid granule inside one document

typedef short bf16x8 __attribute__((ext_vector_type(8)));
typedef float f32x4 __attribute__((ext_vector_type(4)));

__device__ __forceinline__ unsigned f2bf(float f) {
  unsigned u = __float_as_uint(f);
  return (u + 0x7fffu + ((u >> 16) & 1u)) >> 16;   // RNE
}

// One 4-wave block per document b; each body covers TWO sentences (80 rows).
// Wave w owns u-tile w of C[u][s]=wh·h^T over 5 s-tiles. DEFERRED EPILOGUE:
// softmax+out of body t-1 executes inside body t, between MFMA(t) issue and
// e-phase(t), filling the MFMA shadow (hs[(t-1)&1] is safe until B2(t);
// epart is double-buffered). Depth-2 register prefetch, dbuf LDS, 2 barriers.
__global__ __launch_bounds__(256, 3) void doc_kernel(
    const float* __restrict__ inputs, const float* __restrict__ vw,
    const float* __restrict__ wh, const float* __restrict__ wu,
    const float* __restrict__ bw, float* __restrict__ out) {
  __shared__ __align__(16) unsigned short hs[2][TROWS * STRIDE]; // 2x21760 B
  __shared__ __align__(16) float epart[2][5 * 16 * 4];           // dbuf [st][col][w]

  const int tid  = threadIdx.x;
  const int w    = tid >> 6, lane = tid & 63;
  const int col  = lane & 15, grp = lane >> 4;
  const int b    = blockIdx.x;

  const float4* base4 = (const float4*)(inputs + (size_t)b * SP1 * DD);

  // ---- depth-2 prologue: tile 0 -> stA, tile 1 -> stB (clamped granules) ----
  float4 stA[8], stB[8];
  #pragma unroll
  for (int j = 0; j < 8; ++j) stA[j] = base4[min(j * 256 + tid, MAXG)];
  #pragma unroll
  for (int j = 0; j < 8; ++j) stB[j] = base4[min(TGRAN + j * 256 + tid, MAXG)];

  // ---- zero both h buffers once (K-pad cols 100..135 persist) ----
  {
    uint4 z; z.x = z.y = z.z = z.w = 0u;
    uint4* p = (uint4*)&hs[0][0];
    #pragma unroll 1
    for (int i = tid; i < 2 * TROWS * STRIDE / 8; i += 256) p[i] = z;
  }

  // ---- convert-pass byte addresses (fixed per thread) ----
  int cvta[8];
  #pragma unroll
  for (int j = 0; j < 8; ++j) {
    int idx = j * 256 + tid;
    int row = idx / 25, c4 = idx - row * 25;
    cvta[j] = row * 272 + c4 * 8;
  }

  // ---- A fragments: this wave's 16 wh rows (u = 16w + col), resident ----
  bf16x8 afrag[4];
  {
    int u = w * 16 + col;
    #pragma unroll
    for (int kt = 0; kt < 4; ++kt) {
      bf16x8 f;
      #pragma unroll
      for (int j = 0; j < 8; ++j) {
        int k = kt * 32 + grp * 8 + j;
        float v = (u < UU && k < DD) ? wh[u * DD + k] : 0.f;
        f[j] = (short)f2bf(v);
      }
      afrag[kt] = f;
    }
  }

  // ---- wub[u=lane] = uvec[b]·wu[u] + bw[u] (each wave redundantly) ----
  float wubacc;
  {
    int ur = lane < UU ? lane : UU - 1;
    const float4* uv4 = (const float4*)(inputs + ((size_t)b * SP1 + SP1 - 1) * DD);
    const float4* wr4 = (const float4*)(wu + ur * DD);
    float a0 = bw[ur];
    #pragma unroll 5
    for (int q = 0; q < 25; ++q) {
      float4 uq = uv4[q], wq = wr4[q];
      a0 = fmaf(uq.x, wq.x, a0); a0 = fmaf(uq.y, wq.y, a0);
      a0 = fmaf(uq.z, wq.z, a0); a0 = fmaf(uq.w, wq.w, a0);
    }
    wubacc = a0;
  }
  float vwr[4], wubr[4];
  #pragma unroll
  for (int r = 0; r < 4; ++r) {
    int u = w * 16 + grp * 4 + r;
    float wv = __shfl(wubacc, u & 63);
    bool val = (u < UU);
    vwr[r]  = val ? vw[u] : 0.f;
    wubr[r] = val ? wv : 0.f;
  }

  __syncthreads();   // B0: zero-fill visible

  float* outb = out + (size_t)b * NSENT * DD;
  const int sent = w >> 1, dh = w & 1;      // epilogue roles

  // softmax + out for tile-pair pt (reads hs[pt&1], epart[pt&1])
#define EPILOGUE(pt)                                                           \
  {                                                                            \
    const unsigned char* hp_ = (const unsigned char*)&hs[(pt) & 1][0];         \
    const float* ep_ = &epart[(pt) & 1][0];                                    \
    int srow = sent * SEC + (lane < SEC ? lane : 0);                           \
    f32x4 q = *(const f32x4*)&ep_[(srow >> 4) * 64 + (srow & 15) * 4];         \
    float e = (q[0] + q[1]) + (q[2] + q[3]);                                   \
    float p = (lane < SEC) ? __expf(e) : 0.f;                                  \
    float sum = p;                                                             \
    sum += __shfl_xor(sum, 1);                                                 \
    sum += __shfl_xor(sum, 2);                                                 \
    sum += __shfl_xor(sum, 4);                                                 \
    sum += __shfl_xor(sum, 8);                                                 \
    sum += __shfl_xor(sum, 16);                                                \
    sum += __shfl_xor(sum, 32);                                                \
    float pr = p * __builtin_amdgcn_rcpf(sum);                                 \
    /* PIN: compute pr with full exec mask before divergent readlane use */    \
    asm volatile("" : "+v"(pr));                                               \
    if (lane < 50) {                                                           \
      int d = dh * 50 + lane;                                                  \
      const unsigned short* hp = (const unsigned short*)hp_ + sent * SEC * STRIDE + d; \
      float a0 = 0.f, a1 = 0.f;                                                \
      _Pragma("unroll")                                                        \
      for (int s = 0; s < SEC; s += 2) {                                       \
        float al0 = __uint_as_float(__builtin_amdgcn_readlane(__float_as_uint(pr), s));     \
        float al1 = __uint_as_float(__builtin_amdgcn_readlane(__float_as_uint(pr), s + 1)); \
        a0 = fmaf(al0, __uint_as_float((unsigned)hp[s * STRIDE] << 16), a0);   \
        a1 = fmaf(al1, __uint_as_float((unsigned)hp[(s + 1) * STRIDE] << 16), a1); \
      }                                                                        \
      outb[((pt) * 2 + sent) * DD + d] = a0 + a1;                              \
    }                                                                          \
  }

#define TILE_BODY(stg, t)                                                      \
  {                                                                            \
    unsigned char* hc = (unsigned char*)&hs[(t) & 1][0];                       \
    /* convert tile t (stage regs) -> bf16 LDS via v_cvt_pk */                 \
    _Pragma("unroll")                                                          \
    for (int j = 0; j < 8; ++j) {                                              \
      int idx = j * 256 + tid;                                                 \
      if (j < 7 || idx < TGRAN) {                                              \
        unsigned o0, o1;                                                       \
        asm("v_cvt_pk_bf16_f32 %0, %1, %2" : "=v"(o0) : "v"(stg[j].x), "v"(stg[j].y)); \
        asm("v_cvt_pk_bf16_f32 %0, %1, %2" : "=v"(o1) : "v"(stg[j].z), "v"(stg[j].w)); \
        uint2 wv2; wv2.x = o0; wv2.y = o1;                                     \
        *(uint2*)(hc + cvta[j]) = wv2;                                         \
      }                                                                        \
    }                                                                          \
    /* issue tile t+2 loads into the freed stage regs */                       \
    if ((t) + 2 < NSENT / 2) {                                                 \
      _Pragma("unroll")                                                        \
      for (int j = 0; j < 8; ++j)                                              \
        stg[j] = base4[min(((t) + 2) * TGRAN + j * 256 + tid, MAXG)];          \
    }                                                                          \
    __builtin_amdgcn_sched_barrier(0);                                         \
    __syncthreads(); /* B1 */                                                  \
    /* MFMA: acc[st] = C[u-tile w][s-tile st], st 0..4 */                      \
    f32x4 acc[5];                                                              \
    _Pragma("unroll")                                                          \
    for (int st = 0; st < 5; ++st) { f32x4 z = {0.f,0.f,0.f,0.f}; acc[st] = z; } \
    _Pragma("unroll")                                                          \
    for (int kt = 0; kt < 4; ++kt) {                                           \
      _Pragma("unroll")                                                        \
      for (int st = 0; st < 5; ++st) {                                         \
        bf16x8 hf = *(const bf16x8*)(hc + (st * 16 + col) * 272 + kt * 64 + grp * 16); \
        acc[st] = __builtin_amdgcn_mfma_f32_16x16x32_bf16(afrag[kt], hf, acc[st], 0, 0, 0); \
      }                                                                        \
    }                                                                          \
    /* DEFERRED epilogue of tile t-1: overlaps the MFMA shadow */              \
    if ((t) > 0) EPILOGUE((t) - 1);                                            \
    /* partial e[s]: sum over this wave's u rows */                            \
    _Pragma("unroll")                                                          \
    for (int st = 0; st < 5; ++st) {                                           \
      float s = 0.f;                                                           \
      _Pragma("unroll")                                                        \
      for (int r = 0; r < 4; ++r) {                                            \
        float x = acc[st][r] + wubr[r];                                        \
        float E = __expf(2.f * x);                                             \
        float tt = 1.f - 2.f * __builtin_amdgcn_rcpf(E + 1.f);                 \
        s = fmaf(tt, vwr[r], s);                                               \
      }                                                                        \
      s += __shfl_xor(s, 16);                                                  \
      s += __shfl_xor(s, 32);                                                  \
      if (grp == 0) epart[(t) & 1][st * 64 + col * 4 + w] = s;                 \
    }                                                                          \
    __syncthreads(); /* B2: epart[t] visible; hs[(t-1)&1] reads done */        \
  }

  #pragma unroll 1
  for (int t = 0; t < NSENT / 2; t += 2) {
    TILE_BODY(stA, t)
    TILE_BODY(stB, t + 1)
  }
  EPILOGUE(NSENT / 2 - 1)   // tail: softmax+out of the last tile-pair
#undef TILE_BODY
#undef EPILOGUE
}

extern "C" void kernel_launch(void* const* d_in, const int* in_sizes, int n_in,
                              void* d_out, int out_size, void* d_ws, size_t ws_size,
                              hipStream_t stream) {
  const float* inputs = (const float*)d_in[0];
  const float* vw     = (const float*)d_in[1];
  const float* wh     = (const float*)d_in[2];
  const float* wu     = (const float*)d_in[3];
  const float* bw     = (const float*)d_in[4];
  float* out = (float*)d_out;

  doc_kernel<<<NB, 256, 0, stream>>>(inputs, vw, wh, wu, bw, out);
}